// Round 1
// baseline (578.983 us; speedup 1.0000x reference)
//
#include <hip/hip_runtime.h>

// Problem constants (fixed by reference)
#define B_   8
#define S_   1024
#define D_   512
#define DH_  256
#define NH_  4      // heads per branch
#define DEP_ 64     // head depth

// ============================================================
// Fused QKV projection: x(8192,512) @ [6 x W(512,256)] + bias
// Output: six buffers in ws, each head-major (B, NH, S, 64).
// 128x128 block tile, 8x8 per-thread microtile, BK=16.
// ============================================================
__global__ __launch_bounds__(256) void qkv_gemm(
    const float* __restrict__ x,
    const float* __restrict__ W0, const float* __restrict__ W1, const float* __restrict__ W2,
    const float* __restrict__ W3, const float* __restrict__ W4, const float* __restrict__ W5,
    const float* __restrict__ B0, const float* __restrict__ B1, const float* __restrict__ B2,
    const float* __restrict__ B3, const float* __restrict__ B4, const float* __restrict__ B5,
    float* __restrict__ ws)
{
    __shared__ float As[16][132];   // [k][m], padded stride
    __shared__ float Bs[16][128];   // [k][n]

    const int tid = threadIdx.x;
    const int tx  = tid & 15, ty = tid >> 4;
    const int n0  = blockIdx.x * 128;       // 0..1535
    const int m0  = blockIdx.y * 128;       // 0..8191
    const int mat = n0 >> 8;                // which of 6 weight mats
    const int nc0 = n0 & 255;               // 0 or 128 inside the mat

    const float* Ww = (mat==0)?W0:(mat==1)?W1:(mat==2)?W2:(mat==3)?W3:(mat==4)?W4:W5;
    const float* bb = (mat==0)?B0:(mat==1)?B1:(mat==2)?B2:(mat==3)?B3:(mat==4)?B4:B5;

    float acc[8][8];
#pragma unroll
    for (int i=0;i<8;++i)
#pragma unroll
        for (int j=0;j<8;++j) acc[i][j]=0.f;

    for (int k0=0; k0<512; k0+=16) {
#pragma unroll
        for (int l=0;l<2;++l) {             // A tile 128x16 -> As[k][m]
            int e = tid + l*256;
            int r = e >> 2, c4 = (e & 3) << 2;
            const float4 v = *(const float4*)(x + (size_t)(m0+r)*512 + k0 + c4);
            As[c4+0][r]=v.x; As[c4+1][r]=v.y; As[c4+2][r]=v.z; As[c4+3][r]=v.w;
        }
#pragma unroll
        for (int l=0;l<2;++l) {             // B tile 16x128
            int e = tid + l*256;
            int r = e >> 5, c4 = (e & 31) << 2;
            *(float4*)(&Bs[r][c4]) = *(const float4*)(Ww + (size_t)(k0+r)*256 + nc0 + c4);
        }
        __syncthreads();
#pragma unroll
        for (int kk=0;kk<16;++kk) {
            float a[8], b[8];
            *(float4*)&a[0] = *(const float4*)&As[kk][ty*8];
            *(float4*)&a[4] = *(const float4*)&As[kk][ty*8+4];
            *(float4*)&b[0] = *(const float4*)&Bs[kk][tx*8];
            *(float4*)&b[4] = *(const float4*)&Bs[kk][tx*8+4];
#pragma unroll
            for (int i=0;i<8;++i)
#pragma unroll
                for (int j=0;j<8;++j) acc[i][j] = fmaf(a[i], b[j], acc[i][j]);
        }
        __syncthreads();
    }

    float* obuf = ws + (size_t)mat * ((size_t)B_*NH_*S_*DEP_);
#pragma unroll
    for (int i=0;i<8;++i) {
        int m = m0 + ty*8 + i;
        int b = m >> 10, s = m & (S_-1);
#pragma unroll
        for (int j=0;j<8;++j) {
            int nc = nc0 + tx*8 + j;
            int h = nc >> 6, d = nc & 63;
            obuf[(((size_t)(b*NH_+h))*S_ + s)*DEP_ + d] = acc[i][j] + bb[nc];
        }
    }
}

// ============================================================
// Output projection: cat(8192,512) @ Wo(512,512) + bo -> out
// ============================================================
__global__ __launch_bounds__(256) void out_gemm(
    const float* __restrict__ A, const float* __restrict__ W,
    const float* __restrict__ bias, float* __restrict__ out)
{
    __shared__ float As[16][132];
    __shared__ float Bs[16][128];
    const int tid = threadIdx.x;
    const int tx  = tid & 15, ty = tid >> 4;
    const int n0  = blockIdx.x * 128;
    const int m0  = blockIdx.y * 128;

    float acc[8][8];
#pragma unroll
    for (int i=0;i<8;++i)
#pragma unroll
        for (int j=0;j<8;++j) acc[i][j]=0.f;

    for (int k0=0; k0<512; k0+=16) {
#pragma unroll
        for (int l=0;l<2;++l) {
            int e = tid + l*256;
            int r = e >> 2, c4 = (e & 3) << 2;
            const float4 v = *(const float4*)(A + (size_t)(m0+r)*512 + k0 + c4);
            As[c4+0][r]=v.x; As[c4+1][r]=v.y; As[c4+2][r]=v.z; As[c4+3][r]=v.w;
        }
#pragma unroll
        for (int l=0;l<2;++l) {
            int e = tid + l*256;
            int r = e >> 5, c4 = (e & 31) << 2;
            *(float4*)(&Bs[r][c4]) = *(const float4*)(W + (size_t)(k0+r)*512 + n0 + c4);
        }
        __syncthreads();
#pragma unroll
        for (int kk=0;kk<16;++kk) {
            float a[8], b[8];
            *(float4*)&a[0] = *(const float4*)&As[kk][ty*8];
            *(float4*)&a[4] = *(const float4*)&As[kk][ty*8+4];
            *(float4*)&b[0] = *(const float4*)&Bs[kk][tx*8];
            *(float4*)&b[4] = *(const float4*)&Bs[kk][tx*8+4];
#pragma unroll
            for (int i=0;i<8;++i)
#pragma unroll
                for (int j=0;j<8;++j) acc[i][j] = fmaf(a[i], b[j], acc[i][j]);
        }
        __syncthreads();
    }

#pragma unroll
    for (int i=0;i<8;++i) {
        int m = m0 + ty*8 + i;
        float4 o0, o1;
        o0.x=acc[i][0]+bias[n0+tx*8+0]; o0.y=acc[i][1]+bias[n0+tx*8+1];
        o0.z=acc[i][2]+bias[n0+tx*8+2]; o0.w=acc[i][3]+bias[n0+tx*8+3];
        o1.x=acc[i][4]+bias[n0+tx*8+4]; o1.y=acc[i][5]+bias[n0+tx*8+5];
        o1.z=acc[i][6]+bias[n0+tx*8+6]; o1.w=acc[i][7]+bias[n0+tx*8+7];
        *(float4*)(out + (size_t)m*512 + n0 + tx*8)     = o0;
        *(float4*)(out + (size_t)m*512 + n0 + tx*8 + 4) = o1;
    }
}

// ============================================================
// Fused flash-style attention, one branch per template arg.
//  BR=0 (dist): w = softmax(QK^T/8 + m) * softmax(dist + m); out = (sum w V)/(z1*z2)
//  BR=1 (adj):  w = softmax(QK^T/8 + m) * adj;              out = (sum w V)/z1
// Block: 64 q-rows x full head; KT=64 k-tile; 256 threads.
// Thread (qg=tid>>4, e=tid&15):
//   logits phase: rows 4qg+i (i<4), cols 4e+j (j<4), register-blocked
//   PV phase:     rows 4qg+i, d0=(e&7)*8..+7, k-half (e>>3)*32..+31
// All tiles are float4-granule arrays with XOR swizzle to kill bank conflicts.
// w overwrites the dist/adj tile in place (same cells the owning thread read).
// ============================================================
template<int BR>
__global__ __launch_bounds__(256) void attn_fused(
    const float* __restrict__ Qg, const float* __restrict__ Kg, const float* __restrict__ Vg,
    const float* __restrict__ mul, const float* __restrict__ mask,
    float* __restrict__ cat)
{
    __shared__ float4 Qs[64][16];   // [q][k-granule], swizzled by (row>>2)
    __shared__ float4 Ks[64][16];   // [k][depth-granule], swizzled
    __shared__ float4 Vs[64][16];   // [k][depth-granule], plain
    __shared__ float4 Ms[64][16];   // [q][k-granule] dist/adj (+mask), swizzled; becomes w

    const int tid = threadIdx.x;
    const int bh  = blockIdx.y;
    const int b   = bh >> 2, h = bh & 3;
    const int q0  = blockIdx.x * 64;

    const float* Qb  = Qg + ((size_t)bh*S_ + q0)*DEP_;
    const float* Kb  = Kg + (size_t)bh*S_*DEP_;
    const float* Vb  = Vg + (size_t)bh*S_*DEP_;
    const float* Mb  = mul + (size_t)b*S_*S_;
    const float* mkb = mask + (size_t)b*S_;

    const int qg = tid >> 4;       // 0..15
    const int e  = tid & 15;       // 0..15
    const int d0 = (e & 7) * 8;    // PV d base
    const int kh = (e >> 3) * 32;  // PV k-half base

    // Q tile (64x64)
#pragma unroll
    for (int l=0;l<4;++l) {
        int e2 = tid + l*256;
        int r = e2 >> 4, c4 = e2 & 15;
        Qs[r][c4 ^ (r>>2)] = *(const float4*)(Qb + (size_t)r*DEP_ + (c4<<2));
    }

    float m1[4], z1[4], m2[4], z2[4];
#pragma unroll
    for (int i=0;i<4;++i){ m1[i]=-1e30f; z1[i]=0.f; m2[i]=-1e30f; z2[i]=0.f; }
    float oacc[4][8];
#pragma unroll
    for (int i=0;i<4;++i)
#pragma unroll
        for (int j=0;j<8;++j) oacc[i][j]=0.f;

    for (int k0=0; k0<S_; k0+=64) {
        __syncthreads();   // previous PV done before overwriting tiles
#pragma unroll
        for (int l=0;l<4;++l) {            // K (swizzled) + V (plain)
            int e2 = tid + l*256;
            int r = e2 >> 4, c4 = e2 & 15;
            Ks[r][c4 ^ (r>>2)] = *(const float4*)(Kb + (size_t)(k0+r)*DEP_ + (c4<<2));
            Vs[r][c4]          = *(const float4*)(Vb + (size_t)(k0+r)*DEP_ + (c4<<2));
        }
#pragma unroll
        for (int l=0;l<4;++l) {            // dist/adj tile rows = q!
            int e2 = tid + l*256;
            int r = e2 >> 4, c4 = e2 & 15;
            float4 v = *(const float4*)(Mb + (size_t)(q0+r)*S_ + k0 + (c4<<2));
            if (BR==0) {                    // dist softmax gets the additive mask
                const float4 mk = *(const float4*)(mkb + k0 + (c4<<2));
                v.x += mk.x * -1e9f; v.y += mk.y * -1e9f;
                v.z += mk.z * -1e9f; v.w += mk.w * -1e9f;
            }
            Ms[r][c4 ^ (r>>2)] = v;
        }
        __syncthreads();

        // ---- logits (register-blocked 4q x 4k) ----
        float lg[4][4];
#pragma unroll
        for (int i=0;i<4;++i)
#pragma unroll
            for (int j=0;j<4;++j) lg[i][j]=0.f;

        for (int kkg=0; kkg<16; ++kkg) {
            float4 qv[4], kv[4];
#pragma unroll
            for (int i=0;i<4;++i) { int r=4*qg+i; qv[i] = Qs[r][kkg ^ (r>>2)]; }
#pragma unroll
            for (int j=0;j<4;++j) { int r=4*e+j;  kv[j] = Ks[r][kkg ^ (r>>2)]; }
#pragma unroll
            for (int i=0;i<4;++i)
#pragma unroll
                for (int j=0;j<4;++j)
                    lg[i][j] += qv[i].x*kv[j].x + qv[i].y*kv[j].y
                              + qv[i].z*kv[j].z + qv[i].w*kv[j].w;
        }

        // mask for this thread's 4 k columns (k0+4e .. +3)
        const float4 mkv = *(const float4*)(mkb + k0 + 4*e);
        const float mka[4] = {mkv.x*-1e9f, mkv.y*-1e9f, mkv.z*-1e9f, mkv.w*-1e9f};

        float sc[4];
#pragma unroll
        for (int i=0;i<4;++i) {
            const int r = 4*qg+i;
            float4 mt = Ms[r][e ^ (r>>2)];
            float mv[4] = {mt.x, mt.y, mt.z, mt.w};
            float l_[4];
#pragma unroll
            for (int j=0;j<4;++j) l_[j] = lg[i][j]*0.125f + mka[j];

            // online softmax #1 (logits)
            float tm = fmaxf(fmaxf(l_[0],l_[1]), fmaxf(l_[2],l_[3]));
            tm = fmaxf(tm, __shfl_xor(tm,1)); tm = fmaxf(tm, __shfl_xor(tm,2));
            tm = fmaxf(tm, __shfl_xor(tm,4)); tm = fmaxf(tm, __shfl_xor(tm,8));
            float nm = fmaxf(m1[i], tm);
            float s1 = __expf(m1[i] - nm);
            m1[i] = nm;
            float e1[4], rs = 0.f;
#pragma unroll
            for (int j=0;j<4;++j) { e1[j] = __expf(l_[j] - nm); rs += e1[j]; }
            rs += __shfl_xor(rs,1); rs += __shfl_xor(rs,2);
            rs += __shfl_xor(rs,4); rs += __shfl_xor(rs,8);
            z1[i] = z1[i]*s1 + rs;

            float w[4];
            if (BR==0) {
                // online softmax #2 (dist + mask)
                float tm2 = fmaxf(fmaxf(mv[0],mv[1]), fmaxf(mv[2],mv[3]));
                tm2 = fmaxf(tm2, __shfl_xor(tm2,1)); tm2 = fmaxf(tm2, __shfl_xor(tm2,2));
                tm2 = fmaxf(tm2, __shfl_xor(tm2,4)); tm2 = fmaxf(tm2, __shfl_xor(tm2,8));
                float nm2 = fmaxf(m2[i], tm2);
                float s2 = __expf(m2[i] - nm2);
                m2[i] = nm2;
                float e2v[4], rs2 = 0.f;
#pragma unroll
                for (int j=0;j<4;++j) { e2v[j] = __expf(mv[j] - nm2); rs2 += e2v[j]; }
                rs2 += __shfl_xor(rs2,1); rs2 += __shfl_xor(rs2,2);
                rs2 += __shfl_xor(rs2,4); rs2 += __shfl_xor(rs2,8);
                z2[i] = z2[i]*s2 + rs2;
#pragma unroll
                for (int j=0;j<4;++j) w[j] = e1[j]*e2v[j];
                sc[i] = s1*s2;
            } else {
#pragma unroll
                for (int j=0;j<4;++j) w[j] = e1[j]*mv[j];
                sc[i] = s1;
            }
            // in-place: this thread owns exactly these cells
            Ms[r][e ^ (r>>2)] = make_float4(w[0],w[1],w[2],w[3]);
        }
        __syncthreads();

        // ---- PV: rows 4qg+i, 8 d's, 32 k's (half) ----
#pragma unroll
        for (int i=0;i<4;++i)
#pragma unroll
            for (int j=0;j<8;++j) oacc[i][j] *= sc[i];

        for (int s8=0; s8<8; ++s8) {
            const int kkg = (kh>>2) + s8;
            float wv[4][4];
#pragma unroll
            for (int i=0;i<4;++i) {
                int r = 4*qg+i;
                float4 t = Ms[r][kkg ^ (r>>2)];
                wv[i][0]=t.x; wv[i][1]=t.y; wv[i][2]=t.z; wv[i][3]=t.w;
            }
#pragma unroll
            for (int u=0;u<4;++u) {
                const int kk = kkg*4 + u;
                float4 v0 = Vs[kk][(d0>>2)];
                float4 v1 = Vs[kk][(d0>>2)+1];
                float vv[8] = {v0.x,v0.y,v0.z,v0.w,v1.x,v1.y,v1.z,v1.w};
#pragma unroll
                for (int i=0;i<4;++i)
#pragma unroll
                    for (int j=0;j<8;++j)
                        oacc[i][j] = fmaf(wv[i][u], vv[j], oacc[i][j]);
            }
        }
    }

    // merge the two k-halves (lane ^ 8 within the 16-lane group)
#pragma unroll
    for (int i=0;i<4;++i)
#pragma unroll
        for (int j=0;j<8;++j)
            oacc[i][j] += __shfl_xor(oacc[i][j], 8);

    if ((e>>3) == 0) {
#pragma unroll
        for (int i=0;i<4;++i) {
            const float inv = 1.f / (BR==0 ? z1[i]*z2[i] : z1[i]);
            const int qr = q0 + 4*qg + i;
            float* dst = cat + ((size_t)b*S_ + qr)*D_ + BR*DH_ + h*DEP_ + d0;
            float4 o0 = make_float4(oacc[i][0]*inv, oacc[i][1]*inv, oacc[i][2]*inv, oacc[i][3]*inv);
            float4 o1 = make_float4(oacc[i][4]*inv, oacc[i][5]*inv, oacc[i][6]*inv, oacc[i][7]*inv);
            *(float4*)dst     = o0;
            *(float4*)(dst+4) = o1;
        }
    }
}

// ============================================================
extern "C" void kernel_launch(void* const* d_in, const int* in_sizes, int n_in,
                              void* d_out, int out_size, void* d_ws, size_t ws_size,
                              hipStream_t stream)
{
    (void)in_sizes; (void)n_in; (void)out_size; (void)ws_size;

    const float* x    = (const float*)d_in[0];
    const float* mask = (const float*)d_in[1];
    const float* adj  = (const float*)d_in[2];
    const float* dist = (const float*)d_in[3];
    const float* Wqd  = (const float*)d_in[4];  const float* bqd = (const float*)d_in[5];
    const float* Wkd  = (const float*)d_in[6];  const float* bkd = (const float*)d_in[7];
    const float* Wvd  = (const float*)d_in[8];  const float* bvd = (const float*)d_in[9];
    const float* Wqa  = (const float*)d_in[10]; const float* bqa = (const float*)d_in[11];
    const float* Wka  = (const float*)d_in[12]; const float* bka = (const float*)d_in[13];
    const float* Wva  = (const float*)d_in[14]; const float* bva = (const float*)d_in[15];
    const float* Wo   = (const float*)d_in[16]; const float* bo  = (const float*)d_in[17];
    float* out = (float*)d_out;
    float* ws  = (float*)d_ws;

    // ws layout (64 MiB total): 6 head-major QKV buffers + concat buffer
    const size_t bsz = (size_t)B_*NH_*S_*DEP_;   // 2M floats each
    float* qd  = ws + 0*bsz;
    float* kd  = ws + 1*bsz;
    float* vd  = ws + 2*bsz;
    float* qa  = ws + 3*bsz;
    float* ka  = ws + 4*bsz;
    float* va  = ws + 5*bsz;
    float* cat = ws + 6*bsz;                     // 4M floats

    qkv_gemm<<<dim3(12,64), 256, 0, stream>>>(x,
        Wqd,Wkd,Wvd,Wqa,Wka,Wva, bqd,bkd,bvd,bqa,bka,bva, ws);

    attn_fused<0><<<dim3(16,32), 256, 0, stream>>>(qd, kd, vd, dist, mask, cat);
    attn_fused<1><<<dim3(16,32), 256, 0, stream>>>(qa, ka, va, adj,  mask, cat);

    out_gemm<<<dim3(4,64), 256, 0, stream>>>(cat, Wo, bo, out);
}

// Round 2
// 226.742 us; speedup vs baseline: 2.5535x; 2.5535x over previous
//
#include <hip/hip_runtime.h>

typedef __attribute__((ext_vector_type(8))) short bf16x8;
typedef __attribute__((ext_vector_type(4))) float f32x4;
typedef unsigned short ushortT;

#define B_   8
#define S_   1024
#define D_   512
#define DH_  256
#define NH_  4
#define DEP_ 64

__device__ __forceinline__ unsigned short f2bf(float f){
    unsigned u = __builtin_bit_cast(unsigned, f);
    u += 0x7fffu + ((u>>16)&1u);          // round-to-nearest-even
    return (unsigned short)(u>>16);
}
// all hot LDS tiles use 128B rows with XOR-16B swizzle: conflict-free b128 frag reads
__device__ __forceinline__ int swz(int row,int cb){ return (row<<7) + (cb ^ ((row&7)<<4)); }

// ============================================================
// prep: x (f32) -> xb (bf16 row-major [8192][512])
// ============================================================
__global__ __launch_bounds__(256) void prep_x(const float* __restrict__ x, ushortT* __restrict__ xb){
    size_t t = (size_t)blockIdx.x*256 + threadIdx.x;   // 1,048,576 threads, 4 elems each
    float4 v = *(const float4*)(x + t*4);
    ushort4 o; o.x=f2bf(v.x); o.y=f2bf(v.y); o.z=f2bf(v.z); o.w=f2bf(v.w);
    *(ushort4*)(xb + t*4) = o;
}

// ============================================================
// prep: 6x W[512][256] f32 -> Wt[1536][512] bf16 (n-major), bias concat
// ============================================================
__global__ __launch_bounds__(256) void prep_w(
    const float* __restrict__ W0, const float* __restrict__ W1, const float* __restrict__ W2,
    const float* __restrict__ W3, const float* __restrict__ W4, const float* __restrict__ W5,
    const float* __restrict__ B0, const float* __restrict__ B1, const float* __restrict__ B2,
    const float* __restrict__ B3, const float* __restrict__ B4, const float* __restrict__ B5,
    ushortT* __restrict__ Wt, float* __restrict__ bias_all)
{
    int t = blockIdx.x*256 + threadIdx.x;   // 196,608 threads
    int k = t / 384;
    int n4 = (t - k*384)*4;
#pragma unroll
    for (int j=0;j<4;++j){
        int n = n4+j; int mat = n>>8, nc = n&255;
        const float* Wp = (mat==0)?W0:(mat==1)?W1:(mat==2)?W2:(mat==3)?W3:(mat==4)?W4:W5;
        Wt[(size_t)n*512 + k] = f2bf(Wp[(size_t)k*256 + nc]);
    }
    if (t < 384){
#pragma unroll
        for (int j=0;j<4;++j){
            int n = n4+j; int mat = n>>8, nc = n&255;
            const float* Bp = (mat==0)?B0:(mat==1)?B1:(mat==2)?B2:(mat==3)?B3:(mat==4)?B4:B5;
            bias_all[n] = Bp[nc];
        }
    }
}

// ============================================================
// QKV projection, bf16 MFMA. C[m][n] = xb[m][:] . Wt[n][:] + bias
// 128x128 tile, 4 waves (2x2 of 64x64), BK=64.
// Q/K written head-major (b,h,s,d); V written TRANSPOSED (b,h,d,s).
// ============================================================
__global__ __launch_bounds__(256) void qkv_mfma(
    const ushortT* __restrict__ xb, const ushortT* __restrict__ Wt,
    const float* __restrict__ bias_all,
    ushortT* __restrict__ q_d, ushortT* __restrict__ k_d, ushortT* __restrict__ vt_d,
    ushortT* __restrict__ q_a, ushortT* __restrict__ k_a, ushortT* __restrict__ vt_a)
{
    __shared__ __align__(16) char sm[32768];   // As@0 16KB, Bs@16384 16KB
    const int tid = threadIdx.x;
    const int w = tid>>6, l = tid&63, g = l>>4, e = l&15;
    const int wm = w>>1, wn = w&1;
    const int n0 = blockIdx.x*128, m0 = blockIdx.y*128;

    f32x4 acc[4][4];
#pragma unroll
    for (int i=0;i<4;++i)
#pragma unroll
        for (int j=0;j<4;++j) acc[i][j] = (f32x4){0.f,0.f,0.f,0.f};

    for (int k0=0;k0<512;k0+=64){
        __syncthreads();
#pragma unroll
        for (int i=0;i<4;++i){
            int fi = tid + i*256;
            int row = fi>>3, f = fi&7;
            *(uint4*)(sm + swz(row, f*16))         = *(const uint4*)(xb + ((size_t)(m0+row)*512 + k0 + 8*f));
            *(uint4*)(sm + 16384 + swz(row, f*16)) = *(const uint4*)(Wt + ((size_t)(n0+row)*512 + k0 + 8*f));
        }
        __syncthreads();
#pragma unroll
        for (int c=0;c<2;++c){
            bf16x8 a[4];
#pragma unroll
            for (int mt=0;mt<4;++mt)
                a[mt] = *(const bf16x8*)(sm + swz(64*wm + 16*mt + e, g*16 + 64*c));
#pragma unroll
            for (int nt=0;nt<4;++nt){
                bf16x8 bfr = *(const bf16x8*)(sm + 16384 + swz(64*wn + 16*nt + e, g*16 + 64*c));
#pragma unroll
                for (int mt=0;mt<4;++mt)
                    acc[mt][nt] = __builtin_amdgcn_mfma_f32_16x16x32_bf16(a[mt], bfr, acc[mt][nt], 0,0,0);
            }
        }
    }

#pragma unroll
    for (int nt=0;nt<4;++nt){
        int n = n0 + 64*wn + 16*nt + e;
        int mat = n>>8, nc = n&255, h = nc>>6, d = nc&63;
        float bi = bias_all[n];
        ushortT* base = (mat==0)?q_d:(mat==1)?k_d:(mat==2)?vt_d:(mat==3)?q_a:(mat==4)?k_a:vt_a;
        bool isV = (mat==2)||(mat==5);
#pragma unroll
        for (int mt=0;mt<4;++mt){
#pragma unroll
            for (int r=0;r<4;++r){
                int m = m0 + 64*wm + 16*mt + 4*g + r;
                int b = m>>10, s = m&1023;
                unsigned short val = f2bf(acc[mt][nt][r] + bi);
                size_t off = isV ? ((size_t)((b*NH_+h)*DEP_ + d)*S_ + s)
                                 : ((size_t)((b*NH_+h)*S_ + s)*DEP_ + d);
                base[off] = val;
            }
        }
    }
}

// ============================================================
// Flash attention, bf16 MFMA, online (double) softmax in f32.
// Block: 64 q-rows x one (b,h); 4 waves, each owns 16 q-rows.
// KT=64. QK: A=Q[16][64], B=K[k][d] -> logits C rows 4g+r, cols 16kt+e.
// P (unnormalized w) through per-wave swizzled LDS bf16 tile [16][64].
// PV: A=P, B=Vt[d][k]. dist/adj prefetched one step ahead from global.
// ============================================================
template<int BR>
__global__ __launch_bounds__(256) void attn_mfma(
    const ushortT* __restrict__ Qg, const ushortT* __restrict__ Kg, const ushortT* __restrict__ Vtg,
    const float* __restrict__ Mg, const float* __restrict__ mask, float* __restrict__ cat)
{
    __shared__ __align__(16) char sm[36864];
    // Qs@0 8KB; Ks@8192 8KB; Vts@16384 8KB; Ps@24576 (2KB per wave); Msk f32[1024]@32768
    float* Msk = (float*)(sm + 32768);

    const int tid = threadIdx.x;
    const int w = tid>>6, l = tid&63, g = l>>4, e = l&15;
    const int bh = blockIdx.y, b = bh>>2, h = bh&3;
    const int q0 = blockIdx.x*64;

    const ushortT* Qb = Qg + ((size_t)bh*S_ + q0)*DEP_;
    const ushortT* Kb = Kg + (size_t)bh*S_*DEP_;
    const ushortT* Vb = Vtg + (size_t)bh*DEP_*S_;
    const float*   Mb = Mg + (size_t)b*S_*S_ + (size_t)(q0 + 16*w)*S_;
    const float*   mkb = mask + (size_t)b*S_;

#pragma unroll
    for (int i=0;i<2;++i){
        int fi = tid + i*256;
        int row = fi>>3, f = fi&7;
        *(uint4*)(sm + swz(row, f*16)) = *(const uint4*)(Qb + (size_t)row*DEP_ + 8*f);
    }
    for (int i=tid;i<S_;i+=256) Msk[i] = mkb[i] * -1e9f;

    float m1[4], z1[4], m2[4], z2[4];
#pragma unroll
    for (int r=0;r<4;++r){ m1[r]=-1e30f; z1[r]=0.f; m2[r]=-1e30f; z2[r]=0.f; }
    f32x4 oacc[4];
#pragma unroll
    for (int dt=0;dt<4;++dt) oacc[dt] = (f32x4){0.f,0.f,0.f,0.f};

    float Mv[16];
#pragma unroll
    for (int kt=0;kt<4;++kt)
#pragma unroll
        for (int r=0;r<4;++r)
            Mv[kt*4+r] = Mb[(size_t)(4*g + r)*S_ + 16*kt + e];

    for (int s=0;s<16;++s){
        const int k0 = s*64;
        __syncthreads();                     // prior step's LDS reads done
#pragma unroll
        for (int i=0;i<2;++i){
            int fi = tid + i*256;
            int row = fi>>3, f = fi&7;
            *(uint4*)(sm + 8192  + swz(row, f*16)) = *(const uint4*)(Kb + (size_t)(k0+row)*DEP_ + 8*f);
            *(uint4*)(sm + 16384 + swz(row, f*16)) = *(const uint4*)(Vb + (size_t)row*S_ + k0 + 8*f);
        }
        __syncthreads();

        // ---- QK^T ----
        f32x4 lg[4];
#pragma unroll
        for (int kt=0;kt<4;++kt) lg[kt] = (f32x4){0.f,0.f,0.f,0.f};
#pragma unroll
        for (int c=0;c<2;++c){
            bf16x8 aq = *(const bf16x8*)(sm + swz(16*w + e, g*16 + 64*c));
#pragma unroll
            for (int kt=0;kt<4;++kt){
                bf16x8 bk = *(const bf16x8*)(sm + 8192 + swz(16*kt + e, g*16 + 64*c));
                lg[kt] = __builtin_amdgcn_mfma_f32_16x16x32_bf16(aq, bk, lg[kt], 0,0,0);
            }
        }

        // prefetch dist/adj for next step (consumed next iteration)
        float Mn[16];
        {
            const int kp = (s<15) ? k0+64 : 0;
#pragma unroll
            for (int kt=0;kt<4;++kt)
#pragma unroll
                for (int r=0;r<4;++r)
                    Mn[kt*4+r] = Mb[(size_t)(4*g + r)*S_ + kp + 16*kt + e];
        }

        float msk[4];
#pragma unroll
        for (int kt=0;kt<4;++kt) msk[kt] = Msk[k0 + 16*kt + e];

        float sc[4];
#pragma unroll
        for (int r=0;r<4;++r){
            float l_[4];
#pragma unroll
            for (int kt=0;kt<4;++kt) l_[kt] = lg[kt][r]*0.125f + msk[kt];
            float tm = fmaxf(fmaxf(l_[0],l_[1]), fmaxf(l_[2],l_[3]));
            tm = fmaxf(tm, __shfl_xor(tm,1)); tm = fmaxf(tm, __shfl_xor(tm,2));
            tm = fmaxf(tm, __shfl_xor(tm,4)); tm = fmaxf(tm, __shfl_xor(tm,8));
            float nm = fmaxf(m1[r], tm);
            float s1 = __expf(m1[r] - nm);
            m1[r] = nm;
            float e1[4], rs=0.f;
#pragma unroll
            for (int kt=0;kt<4;++kt){ e1[kt] = __expf(l_[kt]-nm); rs += e1[kt]; }
            rs += __shfl_xor(rs,1); rs += __shfl_xor(rs,2);
            rs += __shfl_xor(rs,4); rs += __shfl_xor(rs,8);
            z1[r] = z1[r]*s1 + rs;
            float wv[4];
            if (BR==0){
                float mv[4];
#pragma unroll
                for (int kt=0;kt<4;++kt) mv[kt] = Mv[kt*4+r] + msk[kt];
                float tm2 = fmaxf(fmaxf(mv[0],mv[1]), fmaxf(mv[2],mv[3]));
                tm2 = fmaxf(tm2, __shfl_xor(tm2,1)); tm2 = fmaxf(tm2, __shfl_xor(tm2,2));
                tm2 = fmaxf(tm2, __shfl_xor(tm2,4)); tm2 = fmaxf(tm2, __shfl_xor(tm2,8));
                float nm2 = fmaxf(m2[r], tm2);
                float s2 = __expf(m2[r]-nm2);
                m2[r] = nm2;
                float e2v[4], rs2=0.f;
#pragma unroll
                for (int kt=0;kt<4;++kt){ e2v[kt]=__expf(mv[kt]-nm2); rs2+=e2v[kt]; }
                rs2 += __shfl_xor(rs2,1); rs2 += __shfl_xor(rs2,2);
                rs2 += __shfl_xor(rs2,4); rs2 += __shfl_xor(rs2,8);
                z2[r] = z2[r]*s2 + rs2;
#pragma unroll
                for (int kt=0;kt<4;++kt) wv[kt] = e1[kt]*e2v[kt];
                sc[r] = s1*s2;
            } else {
#pragma unroll
                for (int kt=0;kt<4;++kt) wv[kt] = e1[kt]*Mv[kt*4+r];
                sc[r] = s1;
            }
#pragma unroll
            for (int kt=0;kt<4;++kt)
                *(ushortT*)(sm + 24576 + 2048*w + swz(4*g + r, (16*kt+e)*2)) = f2bf(wv[kt]);
        }
#pragma unroll
        for (int i=0;i<16;++i) Mv[i] = Mn[i];

        // ---- PV ----
        f32x4 scv = {sc[0], sc[1], sc[2], sc[3]};
#pragma unroll
        for (int dt=0;dt<4;++dt) oacc[dt] *= scv;
#pragma unroll
        for (int c=0;c<2;++c){
            bf16x8 ap = *(const bf16x8*)(sm + 24576 + 2048*w + swz(e, g*16 + 64*c));
#pragma unroll
            for (int dt=0;dt<4;++dt){
                bf16x8 bv = *(const bf16x8*)(sm + 16384 + swz(16*dt + e, g*16 + 64*c));
                oacc[dt] = __builtin_amdgcn_mfma_f32_16x16x32_bf16(ap, bv, oacc[dt], 0,0,0);
            }
        }
    }

    float inv[4];
#pragma unroll
    for (int r=0;r<4;++r) inv[r] = 1.f/((BR==0)? z1[r]*z2[r] : z1[r]);
#pragma unroll
    for (int dt=0;dt<4;++dt){
#pragma unroll
        for (int r=0;r<4;++r){
            int q = q0 + 16*w + 4*g + r;
            int c = BR*DH_ + h*DEP_ + 16*dt + e;
            cat[((size_t)b*S_ + q)*D_ + c] = oacc[dt][r]*inv[r];
        }
    }
}

// ============================================================
// Output projection (f32 VALU, proven-accurate): cat @ Wo + bo
// ============================================================
__global__ __launch_bounds__(256) void out_gemm(
    const float* __restrict__ A, const float* __restrict__ W,
    const float* __restrict__ bias, float* __restrict__ out)
{
    __shared__ float As[16][132];
    __shared__ float Bs[16][128];
    const int tid = threadIdx.x;
    const int tx  = tid & 15, ty = tid >> 4;
    const int n0  = blockIdx.x * 128;
    const int m0  = blockIdx.y * 128;

    float acc[8][8];
#pragma unroll
    for (int i=0;i<8;++i)
#pragma unroll
        for (int j=0;j<8;++j) acc[i][j]=0.f;

    for (int k0=0; k0<512; k0+=16) {
#pragma unroll
        for (int l=0;l<2;++l) {
            int e = tid + l*256;
            int r = e >> 2, c4 = (e & 3) << 2;
            const float4 v = *(const float4*)(A + (size_t)(m0+r)*512 + k0 + c4);
            As[c4+0][r]=v.x; As[c4+1][r]=v.y; As[c4+2][r]=v.z; As[c4+3][r]=v.w;
        }
#pragma unroll
        for (int l=0;l<2;++l) {
            int e = tid + l*256;
            int r = e >> 5, c4 = (e & 31) << 2;
            *(float4*)(&Bs[r][c4]) = *(const float4*)(W + (size_t)(k0+r)*512 + n0 + c4);
        }
        __syncthreads();
#pragma unroll
        for (int kk=0;kk<16;++kk) {
            float a[8], b[8];
            *(float4*)&a[0] = *(const float4*)&As[kk][ty*8];
            *(float4*)&a[4] = *(const float4*)&As[kk][ty*8+4];
            *(float4*)&b[0] = *(const float4*)&Bs[kk][tx*8];
            *(float4*)&b[4] = *(const float4*)&Bs[kk][tx*8+4];
#pragma unroll
            for (int i=0;i<8;++i)
#pragma unroll
                for (int j=0;j<8;++j) acc[i][j] = fmaf(a[i], b[j], acc[i][j]);
        }
        __syncthreads();
    }

#pragma unroll
    for (int i=0;i<8;++i) {
        int m = m0 + ty*8 + i;
        float4 o0, o1;
        o0.x=acc[i][0]+bias[n0+tx*8+0]; o0.y=acc[i][1]+bias[n0+tx*8+1];
        o0.z=acc[i][2]+bias[n0+tx*8+2]; o0.w=acc[i][3]+bias[n0+tx*8+3];
        o1.x=acc[i][4]+bias[n0+tx*8+4]; o1.y=acc[i][5]+bias[n0+tx*8+5];
        o1.z=acc[i][6]+bias[n0+tx*8+6]; o1.w=acc[i][7]+bias[n0+tx*8+7];
        *(float4*)(out + (size_t)m*512 + n0 + tx*8)     = o0;
        *(float4*)(out + (size_t)m*512 + n0 + tx*8 + 4) = o1;
    }
}

// ============================================================
extern "C" void kernel_launch(void* const* d_in, const int* in_sizes, int n_in,
                              void* d_out, int out_size, void* d_ws, size_t ws_size,
                              hipStream_t stream)
{
    (void)in_sizes; (void)n_in; (void)out_size; (void)ws_size;

    const float* x    = (const float*)d_in[0];
    const float* mask = (const float*)d_in[1];
    const float* adj  = (const float*)d_in[2];
    const float* dist = (const float*)d_in[3];
    const float* Wqd  = (const float*)d_in[4];  const float* bqd = (const float*)d_in[5];
    const float* Wkd  = (const float*)d_in[6];  const float* bkd = (const float*)d_in[7];
    const float* Wvd  = (const float*)d_in[8];  const float* bvd = (const float*)d_in[9];
    const float* Wqa  = (const float*)d_in[10]; const float* bqa = (const float*)d_in[11];
    const float* Wka  = (const float*)d_in[12]; const float* bka = (const float*)d_in[13];
    const float* Wva  = (const float*)d_in[14]; const float* bva = (const float*)d_in[15];
    const float* Wo   = (const float*)d_in[16]; const float* bo  = (const float*)d_in[17];
    float* out = (float*)d_out;

    char* W = (char*)d_ws;
    ushortT* xb   = (ushortT*)(W + 0);           // 8,388,608 B
    ushortT* Wt   = (ushortT*)(W + 8388608);     // 1,572,864 B
    float*   bias = (float*)  (W + 9961472);     //     6,144 B
    ushortT* q_d  = (ushortT*)(W + 9967616);     // 4,194,304 B each
    ushortT* k_d  = (ushortT*)(W + 14161920);
    ushortT* vt_d = (ushortT*)(W + 18356224);
    ushortT* q_a  = (ushortT*)(W + 22550528);
    ushortT* k_a  = (ushortT*)(W + 26744832);
    ushortT* vt_a = (ushortT*)(W + 30939136);
    float*   cat  = (float*)  (W + 35133440);    // 16,777,216 B -> ends 51,910,656

    prep_x<<<4096, 256, 0, stream>>>(x, xb);
    prep_w<<<768, 256, 0, stream>>>(Wqd,Wkd,Wvd,Wqa,Wka,Wva,
                                    bqd,bkd,bvd,bqa,bka,bva, Wt, bias);
    qkv_mfma<<<dim3(12,64), 256, 0, stream>>>(xb, Wt, bias, q_d,k_d,vt_d, q_a,k_a,vt_a);
    attn_mfma<0><<<dim3(16,32), 256, 0, stream>>>(q_d, k_d, vt_d, dist, mask, cat);
    attn_mfma<1><<<dim3(16,32), 256, 0, stream>>>(q_a, k_a, vt_a, adj,  mask, cat);
    out_gemm<<<dim3(4,64), 256, 0, stream>>>(cat, Wo, bo, out);
}

// Round 3
// 170.398 us; speedup vs baseline: 3.3978x; 1.3307x over previous
//
#include <hip/hip_runtime.h>

typedef __attribute__((ext_vector_type(8))) short bf16x8;
typedef __attribute__((ext_vector_type(4))) float f32x4;
typedef unsigned short ushortT;

#define B_   8
#define S_   1024
#define D_   512
#define DH_  256
#define NH_  4
#define DEP_ 64

__device__ __forceinline__ unsigned short f2bf(float f){
    unsigned u = __builtin_bit_cast(unsigned, f);
    u += 0x7fffu + ((u>>16)&1u);          // round-to-nearest-even
    return (unsigned short)(u>>16);
}
// all hot LDS tiles use 128B rows with XOR-16B swizzle: conflict-free b128 frag reads
__device__ __forceinline__ int swz(int row,int cb){ return (row<<7) + (cb ^ ((row&7)<<4)); }

// ============================================================
// prep: x (f32) -> xb (bf16 row-major [8192][512])
// ============================================================
__global__ __launch_bounds__(256) void prep_x(const float* __restrict__ x, ushortT* __restrict__ xb){
    size_t t = (size_t)blockIdx.x*256 + threadIdx.x;
    float4 v = *(const float4*)(x + t*4);
    ushort4 o; o.x=f2bf(v.x); o.y=f2bf(v.y); o.z=f2bf(v.z); o.w=f2bf(v.w);
    *(ushort4*)(xb + t*4) = o;
}

// ============================================================
// prep: 6x W[512][256] f32 -> Wt[1536][512] bf16 (n-major), bias concat
// ============================================================
__global__ __launch_bounds__(256) void prep_w(
    const float* __restrict__ W0, const float* __restrict__ W1, const float* __restrict__ W2,
    const float* __restrict__ W3, const float* __restrict__ W4, const float* __restrict__ W5,
    const float* __restrict__ B0, const float* __restrict__ B1, const float* __restrict__ B2,
    const float* __restrict__ B3, const float* __restrict__ B4, const float* __restrict__ B5,
    ushortT* __restrict__ Wt, float* __restrict__ bias_all)
{
    int t = blockIdx.x*256 + threadIdx.x;
    int k = t / 384;
    int n4 = (t - k*384)*4;
#pragma unroll
    for (int j=0;j<4;++j){
        int n = n4+j; int mat = n>>8, nc = n&255;
        const float* Wp = (mat==0)?W0:(mat==1)?W1:(mat==2)?W2:(mat==3)?W3:(mat==4)?W4:W5;
        Wt[(size_t)n*512 + k] = f2bf(Wp[(size_t)k*256 + nc]);
    }
    if (t < 384){
#pragma unroll
        for (int j=0;j<4;++j){
            int n = n4+j; int mat = n>>8, nc = n&255;
            const float* Bp = (mat==0)?B0:(mat==1)?B1:(mat==2)?B2:(mat==3)?B3:(mat==4)?B4:B5;
            bias_all[n] = Bp[nc];
        }
    }
}

// ============================================================
// prep: Wo[512][512] f32 -> Wot[512][512] bf16 (n-major), LDS transpose
// ============================================================
__global__ __launch_bounds__(256) void prep_wo(const float* __restrict__ Wo, ushortT* __restrict__ Wot){
    __shared__ float t[32][33];
    const int k0 = blockIdx.y*32, n0 = blockIdx.x*32;
    const int ty = threadIdx.x>>5, tx = threadIdx.x&31;
#pragma unroll
    for (int i=0;i<4;++i)
        t[ty+8*i][tx] = Wo[(size_t)(k0+ty+8*i)*512 + n0+tx];
    __syncthreads();
#pragma unroll
    for (int i=0;i<4;++i)
        Wot[(size_t)(n0+ty+8*i)*512 + k0+tx] = f2bf(t[tx][ty+8*i]);
}

// ============================================================
// QKV projection, bf16 MFMA. C[m][n] = xb[m][:] . Wt[n][:] + bias
// 128x128 tile, 4 waves (2x2 of 64x64), BK=64.
// Q/K written head-major (b,h,s,d); V written TRANSPOSED (b,h,d,s).
// ============================================================
__global__ __launch_bounds__(256) void qkv_mfma(
    const ushortT* __restrict__ xb, const ushortT* __restrict__ Wt,
    const float* __restrict__ bias_all,
    ushortT* __restrict__ q_d, ushortT* __restrict__ k_d, ushortT* __restrict__ vt_d,
    ushortT* __restrict__ q_a, ushortT* __restrict__ k_a, ushortT* __restrict__ vt_a)
{
    __shared__ __align__(16) char sm[32768];   // As@0 16KB, Bs@16384 16KB
    const int tid = threadIdx.x;
    const int w = tid>>6, l = tid&63, g = l>>4, e = l&15;
    const int wm = w>>1, wn = w&1;
    const int n0 = blockIdx.x*128, m0 = blockIdx.y*128;

    f32x4 acc[4][4];
#pragma unroll
    for (int i=0;i<4;++i)
#pragma unroll
        for (int j=0;j<4;++j) acc[i][j] = (f32x4){0.f,0.f,0.f,0.f};

    for (int k0=0;k0<512;k0+=64){
        __syncthreads();
#pragma unroll
        for (int i=0;i<4;++i){
            int fi = tid + i*256;
            int row = fi>>3, f = fi&7;
            *(uint4*)(sm + swz(row, f*16))         = *(const uint4*)(xb + ((size_t)(m0+row)*512 + k0 + 8*f));
            *(uint4*)(sm + 16384 + swz(row, f*16)) = *(const uint4*)(Wt + ((size_t)(n0+row)*512 + k0 + 8*f));
        }
        __syncthreads();
#pragma unroll
        for (int c=0;c<2;++c){
            bf16x8 a[4];
#pragma unroll
            for (int mt=0;mt<4;++mt)
                a[mt] = *(const bf16x8*)(sm + swz(64*wm + 16*mt + e, g*16 + 64*c));
#pragma unroll
            for (int nt=0;nt<4;++nt){
                bf16x8 bfr = *(const bf16x8*)(sm + 16384 + swz(64*wn + 16*nt + e, g*16 + 64*c));
#pragma unroll
                for (int mt=0;mt<4;++mt)
                    acc[mt][nt] = __builtin_amdgcn_mfma_f32_16x16x32_bf16(a[mt], bfr, acc[mt][nt], 0,0,0);
            }
        }
    }

#pragma unroll
    for (int nt=0;nt<4;++nt){
        int n = n0 + 64*wn + 16*nt + e;
        int mat = n>>8, nc = n&255, h = nc>>6, d = nc&63;
        float bi = bias_all[n];
        ushortT* base = (mat==0)?q_d:(mat==1)?k_d:(mat==2)?vt_d:(mat==3)?q_a:(mat==4)?k_a:vt_a;
        bool isV = (mat==2)||(mat==5);
#pragma unroll
        for (int mt=0;mt<4;++mt){
#pragma unroll
            for (int r=0;r<4;++r){
                int m = m0 + 64*wm + 16*mt + 4*g + r;
                int b = m>>10, s = m&1023;
                unsigned short val = f2bf(acc[mt][nt][r] + bi);
                size_t off = isV ? ((size_t)((b*NH_+h)*DEP_ + d)*S_ + s)
                                 : ((size_t)((b*NH_+h)*S_ + s)*DEP_ + d);
                base[off] = val;
            }
        }
    }
}

// ============================================================
// Flash attention, bf16 MFMA, online (double) softmax in f32.
// Writes cat as bf16 (A operand of the out projection).
// ============================================================
template<int BR>
__global__ __launch_bounds__(256) void attn_mfma(
    const ushortT* __restrict__ Qg, const ushortT* __restrict__ Kg, const ushortT* __restrict__ Vtg,
    const float* __restrict__ Mg, const float* __restrict__ mask, ushortT* __restrict__ cat)
{
    __shared__ __align__(16) char sm[36864];
    // Qs@0 8KB; Ks@8192 8KB; Vts@16384 8KB; Ps@24576 (2KB per wave); Msk f32[1024]@32768
    float* Msk = (float*)(sm + 32768);

    const int tid = threadIdx.x;
    const int w = tid>>6, l = tid&63, g = l>>4, e = l&15;
    const int bh = blockIdx.y, b = bh>>2, h = bh&3;
    const int q0 = blockIdx.x*64;

    const ushortT* Qb = Qg + ((size_t)bh*S_ + q0)*DEP_;
    const ushortT* Kb = Kg + (size_t)bh*S_*DEP_;
    const ushortT* Vb = Vtg + (size_t)bh*DEP_*S_;
    const float*   Mb = Mg + (size_t)b*S_*S_ + (size_t)(q0 + 16*w)*S_;
    const float*   mkb = mask + (size_t)b*S_;

#pragma unroll
    for (int i=0;i<2;++i){
        int fi = tid + i*256;
        int row = fi>>3, f = fi&7;
        *(uint4*)(sm + swz(row, f*16)) = *(const uint4*)(Qb + (size_t)row*DEP_ + 8*f);
    }
    for (int i=tid;i<S_;i+=256) Msk[i] = mkb[i] * -1e9f;

    float m1[4], z1[4], m2[4], z2[4];
#pragma unroll
    for (int r=0;r<4;++r){ m1[r]=-1e30f; z1[r]=0.f; m2[r]=-1e30f; z2[r]=0.f; }
    f32x4 oacc[4];
#pragma unroll
    for (int dt=0;dt<4;++dt) oacc[dt] = (f32x4){0.f,0.f,0.f,0.f};

    float Mv[16];
#pragma unroll
    for (int kt=0;kt<4;++kt)
#pragma unroll
        for (int r=0;r<4;++r)
            Mv[kt*4+r] = Mb[(size_t)(4*g + r)*S_ + 16*kt + e];

    for (int s=0;s<16;++s){
        const int k0 = s*64;
        __syncthreads();                     // prior step's LDS reads done
#pragma unroll
        for (int i=0;i<2;++i){
            int fi = tid + i*256;
            int row = fi>>3, f = fi&7;
            *(uint4*)(sm + 8192  + swz(row, f*16)) = *(const uint4*)(Kb + (size_t)(k0+row)*DEP_ + 8*f);
            *(uint4*)(sm + 16384 + swz(row, f*16)) = *(const uint4*)(Vb + (size_t)row*S_ + k0 + 8*f);
        }
        __syncthreads();

        // ---- QK^T ----
        f32x4 lg[4];
#pragma unroll
        for (int kt=0;kt<4;++kt) lg[kt] = (f32x4){0.f,0.f,0.f,0.f};
#pragma unroll
        for (int c=0;c<2;++c){
            bf16x8 aq = *(const bf16x8*)(sm + swz(16*w + e, g*16 + 64*c));
#pragma unroll
            for (int kt=0;kt<4;++kt){
                bf16x8 bk = *(const bf16x8*)(sm + 8192 + swz(16*kt + e, g*16 + 64*c));
                lg[kt] = __builtin_amdgcn_mfma_f32_16x16x32_bf16(aq, bk, lg[kt], 0,0,0);
            }
        }

        // prefetch dist/adj for next step (consumed next iteration)
        float Mn[16];
        {
            const int kp = (s<15) ? k0+64 : 0;
#pragma unroll
            for (int kt=0;kt<4;++kt)
#pragma unroll
                for (int r=0;r<4;++r)
                    Mn[kt*4+r] = Mb[(size_t)(4*g + r)*S_ + kp + 16*kt + e];
        }

        float msk[4];
#pragma unroll
        for (int kt=0;kt<4;++kt) msk[kt] = Msk[k0 + 16*kt + e];

        float sc[4];
#pragma unroll
        for (int r=0;r<4;++r){
            float l_[4];
#pragma unroll
            for (int kt=0;kt<4;++kt) l_[kt] = lg[kt][r]*0.125f + msk[kt];
            float tm = fmaxf(fmaxf(l_[0],l_[1]), fmaxf(l_[2],l_[3]));
            tm = fmaxf(tm, __shfl_xor(tm,1)); tm = fmaxf(tm, __shfl_xor(tm,2));
            tm = fmaxf(tm, __shfl_xor(tm,4)); tm = fmaxf(tm, __shfl_xor(tm,8));
            float nm = fmaxf(m1[r], tm);
            float s1 = __expf(m1[r] - nm);
            m1[r] = nm;
            float e1[4], rs=0.f;
#pragma unroll
            for (int kt=0;kt<4;++kt){ e1[kt] = __expf(l_[kt]-nm); rs += e1[kt]; }
            rs += __shfl_xor(rs,1); rs += __shfl_xor(rs,2);
            rs += __shfl_xor(rs,4); rs += __shfl_xor(rs,8);
            z1[r] = z1[r]*s1 + rs;
            float wv[4];
            if (BR==0){
                float mv[4];
#pragma unroll
                for (int kt=0;kt<4;++kt) mv[kt] = Mv[kt*4+r] + msk[kt];
                float tm2 = fmaxf(fmaxf(mv[0],mv[1]), fmaxf(mv[2],mv[3]));
                tm2 = fmaxf(tm2, __shfl_xor(tm2,1)); tm2 = fmaxf(tm2, __shfl_xor(tm2,2));
                tm2 = fmaxf(tm2, __shfl_xor(tm2,4)); tm2 = fmaxf(tm2, __shfl_xor(tm2,8));
                float nm2 = fmaxf(m2[r], tm2);
                float s2 = __expf(m2[r]-nm2);
                m2[r] = nm2;
                float e2v[4], rs2=0.f;
#pragma unroll
                for (int kt=0;kt<4;++kt){ e2v[kt]=__expf(mv[kt]-nm2); rs2+=e2v[kt]; }
                rs2 += __shfl_xor(rs2,1); rs2 += __shfl_xor(rs2,2);
                rs2 += __shfl_xor(rs2,4); rs2 += __shfl_xor(rs2,8);
                z2[r] = z2[r]*s2 + rs2;
#pragma unroll
                for (int kt=0;kt<4;++kt) wv[kt] = e1[kt]*e2v[kt];
                sc[r] = s1*s2;
            } else {
#pragma unroll
                for (int kt=0;kt<4;++kt) wv[kt] = e1[kt]*Mv[kt*4+r];
                sc[r] = s1;
            }
#pragma unroll
            for (int kt=0;kt<4;++kt)
                *(ushortT*)(sm + 24576 + 2048*w + swz(4*g + r, (16*kt+e)*2)) = f2bf(wv[kt]);
        }
#pragma unroll
        for (int i=0;i<16;++i) Mv[i] = Mn[i];

        // ---- PV ----
        f32x4 scv = {sc[0], sc[1], sc[2], sc[3]};
#pragma unroll
        for (int dt=0;dt<4;++dt) oacc[dt] *= scv;
#pragma unroll
        for (int c=0;c<2;++c){
            bf16x8 ap = *(const bf16x8*)(sm + 24576 + 2048*w + swz(e, g*16 + 64*c));
#pragma unroll
            for (int dt=0;dt<4;++dt){
                bf16x8 bv = *(const bf16x8*)(sm + 16384 + swz(16*dt + e, g*16 + 64*c));
                oacc[dt] = __builtin_amdgcn_mfma_f32_16x16x32_bf16(ap, bv, oacc[dt], 0,0,0);
            }
        }
    }

    float inv[4];
#pragma unroll
    for (int r=0;r<4;++r) inv[r] = 1.f/((BR==0)? z1[r]*z2[r] : z1[r]);
#pragma unroll
    for (int dt=0;dt<4;++dt){
#pragma unroll
        for (int r=0;r<4;++r){
            int q = q0 + 16*w + 4*g + r;
            int c = BR*DH_ + h*DEP_ + 16*dt + e;
            cat[((size_t)b*S_ + q)*D_ + c] = f2bf(oacc[dt][r]*inv[r]);
        }
    }
}

// ============================================================
// Output projection, bf16 MFMA: out[m][n] = catb[m][:].Wot[n][:] + bo[n]
// 128x128 tile, 4 waves (2x2 of 64x64), BK=64, f32 output.
// ============================================================
__global__ __launch_bounds__(256) void out_mfma(
    const ushortT* __restrict__ catb, const ushortT* __restrict__ Wot,
    const float* __restrict__ bo, float* __restrict__ out)
{
    __shared__ __align__(16) char sm[32768];   // As@0 16KB, Bs@16384 16KB
    const int tid = threadIdx.x;
    const int w = tid>>6, l = tid&63, g = l>>4, e = l&15;
    const int wm = w>>1, wn = w&1;
    const int n0 = blockIdx.x*128, m0 = blockIdx.y*128;

    f32x4 acc[4][4];
#pragma unroll
    for (int i=0;i<4;++i)
#pragma unroll
        for (int j=0;j<4;++j) acc[i][j] = (f32x4){0.f,0.f,0.f,0.f};

    for (int k0=0;k0<512;k0+=64){
        __syncthreads();
#pragma unroll
        for (int i=0;i<4;++i){
            int fi = tid + i*256;
            int row = fi>>3, f = fi&7;
            *(uint4*)(sm + swz(row, f*16))         = *(const uint4*)(catb + ((size_t)(m0+row)*512 + k0 + 8*f));
            *(uint4*)(sm + 16384 + swz(row, f*16)) = *(const uint4*)(Wot  + ((size_t)(n0+row)*512 + k0 + 8*f));
        }
        __syncthreads();
#pragma unroll
        for (int c=0;c<2;++c){
            bf16x8 a[4];
#pragma unroll
            for (int mt=0;mt<4;++mt)
                a[mt] = *(const bf16x8*)(sm + swz(64*wm + 16*mt + e, g*16 + 64*c));
#pragma unroll
            for (int nt=0;nt<4;++nt){
                bf16x8 bfr = *(const bf16x8*)(sm + 16384 + swz(64*wn + 16*nt + e, g*16 + 64*c));
#pragma unroll
                for (int mt=0;mt<4;++mt)
                    acc[mt][nt] = __builtin_amdgcn_mfma_f32_16x16x32_bf16(a[mt], bfr, acc[mt][nt], 0,0,0);
            }
        }
    }

#pragma unroll
    for (int nt=0;nt<4;++nt){
        int n = n0 + 64*wn + 16*nt + e;
        float bi = bo[n];
#pragma unroll
        for (int mt=0;mt<4;++mt){
#pragma unroll
            for (int r=0;r<4;++r){
                int m = m0 + 64*wm + 16*mt + 4*g + r;
                out[(size_t)m*512 + n] = acc[mt][nt][r] + bi;
            }
        }
    }
}

// ============================================================
extern "C" void kernel_launch(void* const* d_in, const int* in_sizes, int n_in,
                              void* d_out, int out_size, void* d_ws, size_t ws_size,
                              hipStream_t stream)
{
    (void)in_sizes; (void)n_in; (void)out_size; (void)ws_size;

    const float* x    = (const float*)d_in[0];
    const float* mask = (const float*)d_in[1];
    const float* adj  = (const float*)d_in[2];
    const float* dist = (const float*)d_in[3];
    const float* Wqd  = (const float*)d_in[4];  const float* bqd = (const float*)d_in[5];
    const float* Wkd  = (const float*)d_in[6];  const float* bkd = (const float*)d_in[7];
    const float* Wvd  = (const float*)d_in[8];  const float* bvd = (const float*)d_in[9];
    const float* Wqa  = (const float*)d_in[10]; const float* bqa = (const float*)d_in[11];
    const float* Wka  = (const float*)d_in[12]; const float* bka = (const float*)d_in[13];
    const float* Wva  = (const float*)d_in[14]; const float* bva = (const float*)d_in[15];
    const float* Wo   = (const float*)d_in[16]; const float* bo  = (const float*)d_in[17];
    float* out = (float*)d_out;

    char* W = (char*)d_ws;
    ushortT* xb   = (ushortT*)(W + 0);           //  8,388,608 B
    ushortT* Wt   = (ushortT*)(W + 8388608);     //  1,572,864 B
    float*   bias = (float*)  (W + 9961472);     //      6,144 B
    ushortT* q_d  = (ushortT*)(W + 9967616);     //  4,194,304 B each
    ushortT* k_d  = (ushortT*)(W + 14161920);
    ushortT* vt_d = (ushortT*)(W + 18356224);
    ushortT* q_a  = (ushortT*)(W + 22550528);
    ushortT* k_a  = (ushortT*)(W + 26744832);
    ushortT* vt_a = (ushortT*)(W + 30939136);
    ushortT* catb = (ushortT*)(W + 35133440);    //  8,388,608 B
    ushortT* Wot  = (ushortT*)(W + 43522048);    //    524,288 B -> ends 44,046,336

    prep_x<<<4096, 256, 0, stream>>>(x, xb);
    prep_w<<<768, 256, 0, stream>>>(Wqd,Wkd,Wvd,Wqa,Wka,Wva,
                                    bqd,bkd,bvd,bqa,bka,bva, Wt, bias);
    prep_wo<<<dim3(16,16), 256, 0, stream>>>(Wo, Wot);
    qkv_mfma<<<dim3(12,64), 256, 0, stream>>>(xb, Wt, bias, q_d,k_d,vt_d, q_a,k_a,vt_a);
    attn_mfma<0><<<dim3(16,32), 256, 0, stream>>>(q_d, k_d, vt_d, dist, mask, catb);
    attn_mfma<1><<<dim3(16,32), 256, 0, stream>>>(q_a, k_a, vt_a, adj,  mask, catb);
    out_mfma<<<dim3(4,64), 256, 0, stream>>>(catb, Wot, bo, out);
}